// Round 7
// baseline (165.593 us; speedup 1.0000x reference)
//
#include <hip/hip_runtime.h>

// dims from the reference
#define BB 2
#define PP 512
#define NN 8
#define HH 32

typedef float f4     __attribute__((ext_vector_type(4)));
typedef float f32x4  __attribute__((ext_vector_type(4)));
typedef short bf16x8 __attribute__((ext_vector_type(8)));

// float -> bf16 bits, round-nearest-even
__device__ __forceinline__ short f2bf(float f) {
  union { float f; unsigned u; } v; v.f = f;
  unsigned r = v.u + 0x7FFFu + ((v.u >> 16) & 1u);
  return (short)(r >> 16);
}

// ---------------------------------------------------------------------------
// Kernel 0 (aux): blocks 0..255  : WT[n][h1][h3][h2] = W[n][h1][h2][h3]
//                 blocks 256..383: eBf tiled bf16 layout:
//   eBf[b][pt][n][l*8+j] = bf16( e[b, pt*16 + (l&15), n, (l>>4)*8 + j] )
//   -> vmain's B-fragment is ONE dense 1KB wave load.
// ---------------------------------------------------------------------------
__global__ __launch_bounds__(256) void aux_kernel(
    const float* __restrict__ W, const float* __restrict__ e,
    float* __restrict__ WT, short* __restrict__ eBf) {
  const int bid = blockIdx.x;
  const int t   = threadIdx.x;

  if (bid < 256) {                     // ---- W transpose (32x32 per block) ----
    __shared__ float ls[32][33];
    const float* src = W  + (size_t)bid * 1024;
    float*       dst = WT + (size_t)bid * 1024;
    #pragma unroll
    for (int r = 0; r < 4; ++r) {
      const int h2 = r * 8 + (t >> 5), h3 = t & 31;
      ls[h2][h3] = src[h2 * 32 + h3];
    }
    __syncthreads();
    #pragma unroll
    for (int r = 0; r < 4; ++r) {
      const int h3 = r * 8 + (t >> 5), h2 = t & 31;
      dst[h3 * 32 + h2] = ls[h2][h3];
    }
  } else {                             // ---- e -> bf16, tiled fragment layout ----
    const int ft = (bid - 256) * 256 + t;      // 0..32767
    const int l  = ft & 63;
    const int n  = (ft >> 6) & 7;
    const int pt = (ft >> 9) & 31;
    const int b  = ft >> 14;
    const float* src =
        e + (((size_t)(b * PP + pt * 16 + (l & 15)) * NN + n) * HH + (l >> 4) * 8);
    const f4 e0 = *(const f4*)src;
    const f4 e1 = *(const f4*)(src + 4);
    bf16x8 v;
    v[0] = f2bf(e0[0]); v[1] = f2bf(e0[1]); v[2] = f2bf(e0[2]); v[3] = f2bf(e0[3]);
    v[4] = f2bf(e1[0]); v[5] = f2bf(e1[1]); v[6] = f2bf(e1[2]); v[7] = f2bf(e1[3]);
    *(bf16x8*)(eBf + (size_t)ft * 8) = v;
  }
}

// ---------------------------------------------------------------------------
// Kernel 1: prep2 — tmpT[b,p1,n,h3,h2] = bf16( sum_h1 d * WT ), 16B stores.
// (round-3 version: coalesced WT loads, dense bf16x8 stores, ~8 us)
// ---------------------------------------------------------------------------
__global__ __launch_bounds__(256) void prep2_kernel(
    const float* __restrict__ d, const float* __restrict__ WT,
    short* __restrict__ tmpT) {
  const int bid    = blockIdx.x;       // 0..511
  const int b      = bid >> 8;
  const int rem    = bid & 255;
  const int npair  = rem >> 6;         // 0..3
  const int p1base = (rem & 63) * 8;
  const int t      = threadIdx.x;

  __shared__ float dsh[2][32][8];      // [n'][h1][p1l]
  {
    const int h1 = t & 31, p1l = (t >> 5) & 7;
    #pragma unroll
    for (int r = 0; r < 2; ++r)
      dsh[r][h1][p1l] =
          d[(size_t)((b * PP + p1base + p1l) * NN + npair * 2 + r) * HH + h1];
  }
  __syncthreads();

  const int np  = t >> 7;              // 0/1
  const int h3  = (t >> 2) & 31;
  const int h2g = t & 3;               // h2 base = h2g*8
  const int n   = npair * 2 + np;

  float acc[8][8];                     // [p1l][h2loc]
  #pragma unroll
  for (int p = 0; p < 8; ++p)
    #pragma unroll
    for (int q = 0; q < 8; ++q) acc[p][q] = 0.f;

  const float* wb = WT + ((size_t)(n * HH) * HH + h3) * HH + h2g * 8;
  for (int h1 = 0; h1 < 32; ++h1) {
    const f4 w0 = *(const f4*)(wb + (size_t)h1 * 1024);
    const f4 w1 = *(const f4*)(wb + (size_t)h1 * 1024 + 4);
    const f4 d0 = *(const f4*)&dsh[np][h1][0];
    const f4 d1 = *(const f4*)&dsh[np][h1][4];
    #pragma unroll
    for (int p = 0; p < 4; ++p) {
      #pragma unroll
      for (int q = 0; q < 4; ++q) {
        acc[p][q]         = fmaf(d0[p], w0[q], acc[p][q]);
        acc[p][q + 4]     = fmaf(d0[p], w1[q], acc[p][q + 4]);
        acc[p + 4][q]     = fmaf(d1[p], w0[q], acc[p + 4][q]);
        acc[p + 4][q + 4] = fmaf(d1[p], w1[q], acc[p + 4][q + 4]);
      }
    }
  }

  const size_t obase =
      ((size_t)(b * PP + p1base) * NN + n) * (HH * HH) + h3 * 32 + h2g * 8;
  #pragma unroll
  for (int p = 0; p < 8; ++p) {
    bf16x8 v;
    #pragma unroll
    for (int q = 0; q < 8; ++q) v[q] = f2bf(acc[p][q]);
    *(bf16x8*)(tmpT + obase + (size_t)p * (NN * HH * HH)) = v;
  }
}

// ---------------------------------------------------------------------------
// Kernel 2: vmain v7 — MAX OCCUPANCY (32 waves/CU = 8 blocks x 4 waves).
//   LDS 16 KB (per-wave transpose quarters only). VGPR <= 64 via
//   __launch_bounds__(256,8): A-frags re-read from tmpT each quarter
//   (16 KB/block slice -> L1 hits) instead of 64 pinned VGPRs.
//   B-frags: single dense 1KB wave load from tiled eBf.
//   Store path: XOR-swizzled lbuf transpose -> 4x256B-dense dwordx4.
// ---------------------------------------------------------------------------
__global__ __launch_bounds__(256, 8) void vmain_kernel(
    const short* __restrict__ eBf, const short* __restrict__ tmpT,
    float* __restrict__ out) {
  const int bid = blockIdx.x;
  const int b   = bid >> 9;
  const int p1  = bid & 511;
  const int t   = threadIdx.x;
  const int wv  = t >> 6;
  const int l   = t & 63;
  const int lr  = l & 15;
  const int lk  = l >> 4;

  __shared__ float lbuf[4][16][64];    // 16 KB per-wave transpose buffers
  float*       wl   = &lbuf[wv][0][0];
  const short* tb   = tmpT + (size_t)(b * PP + p1) * (NN * HH * HH);
  const short* eb   = eBf + (size_t)b * (32 * NN * 512);
  float*       outb = out + (size_t)(b * PP + p1) * (PP * NN * HH);
  const f32x4  z    = {0.f, 0.f, 0.f, 0.f};
  const int    sw   = lr & 7;

  for (int i = 0; i < 8; ++i) {
    const int pt = wv * 8 + i;         // p2 tile index
    const int m0 = pt * 16;
    #pragma unroll
    for (int q = 0; q < 4; ++q) {
      const int n0 = q * 2;
      // A-fragments from tmpT (L1-resident): rows h3 = c*16+lr, k = lk*8+j
      const bf16x8 f00 = *(const bf16x8*)(tb + (n0 + 0) * 1024 + lr * 32 + lk * 8);
      const bf16x8 f01 = *(const bf16x8*)(tb + (n0 + 0) * 1024 + (16 + lr) * 32 + lk * 8);
      const bf16x8 f10 = *(const bf16x8*)(tb + (n0 + 1) * 1024 + lr * 32 + lk * 8);
      const bf16x8 f11 = *(const bf16x8*)(tb + (n0 + 1) * 1024 + (16 + lr) * 32 + lk * 8);
      // B-fragments: dense 1KB wave loads from tiled eBf
      const bf16x8 a0 = *(const bf16x8*)(eb + ((size_t)(pt * NN + n0) << 9) + l * 8);
      const bf16x8 a1 = *(const bf16x8*)(eb + ((size_t)(pt * NN + n0 + 1) << 9) + l * 8);
      const f32x4 c00 = __builtin_amdgcn_mfma_f32_16x16x32_bf16(f00, a0, z, 0, 0, 0);
      const f32x4 c01 = __builtin_amdgcn_mfma_f32_16x16x32_bf16(f01, a0, z, 0, 0, 0);
      const f32x4 c10 = __builtin_amdgcn_mfma_f32_16x16x32_bf16(f10, a1, z, 0, 0, 0);
      const f32x4 c11 = __builtin_amdgcn_mfma_f32_16x16x32_bf16(f11, a1, z, 0, 0, 0);
      // swizzled per-wave LDS transpose (verified mapping from v6)
      *(f32x4*)(wl + lr * 64 + ((lk)      ^ sw) * 4) = c00;
      *(f32x4*)(wl + lr * 64 + ((4 + lk)  ^ sw) * 4) = c01;
      *(f32x4*)(wl + lr * 64 + ((8 + lk)  ^ sw) * 4) = c10;
      *(f32x4*)(wl + lr * 64 + ((12 + lk) ^ sw) * 4) = c11;
      // transpose read + dense store (4 rows x 256B per instruction)
      #pragma unroll
      for (int j = 0; j < 4; ++j) {
        const int row = 4 * j + lk;
        const f32x4 v = *(const f32x4*)(wl + row * 64 + ((lr ^ (row & 7)) * 4));
        *(f32x4*)(outb + (size_t)(m0 + row) * (NN * HH) + n0 * HH + lr * 4) = v;
      }
    }
  }
}

// ---------------------------------------------------------------------------
// Fallback (no/small ws): self-contained fused kernel (correct, slower).
// ---------------------------------------------------------------------------
__global__ __launch_bounds__(256, 4) void fused_kernel(
    const float* __restrict__ d, const float* __restrict__ e,
    const float* __restrict__ W, float* __restrict__ out) {
  const int bid = blockIdx.x;
  const int b   = bid >> 9;
  const int p1  = bid & 511;
  const int t   = threadIdx.x;

  __shared__ float dsh[NN * HH];
  __shared__ short tsh[NN * HH * HH];
  dsh[t] = d[(size_t)(b * PP + p1) * (NN * HH) + t];
  __syncthreads();

  const int h3  = t & 31;
  const int h2b = t >> 5;
  for (int n = 0; n < 8; ++n) {
    f4 dv[8];
    #pragma unroll
    for (int j = 0; j < 8; ++j) dv[j] = *(const f4*)&dsh[n * 32 + j * 4];
    const float* Wn = W + (size_t)n * (HH * HH * HH);
    #pragma unroll
    for (int h2s = 0; h2s < 4; ++h2s) {
      const int h2 = h2s * 8 + h2b;
      float acc = 0.f;
      #pragma unroll
      for (int j = 0; j < 8; ++j)
        #pragma unroll
        for (int k = 0; k < 4; ++k)
          acc = fmaf(dv[j][k], Wn[(j * 4 + k) * 1024 + h2 * 32 + h3], acc);
      tsh[n * 1024 + h3 * 32 + h2] = f2bf(acc);
    }
  }
  __syncthreads();

  const int wv = t >> 6;
  const int l  = t & 63;
  const int lr = l & 15;
  const int lk = l >> 4;
  bf16x8 bfr[8][2];
  #pragma unroll
  for (int n = 0; n < 8; ++n)
    #pragma unroll
    for (int c = 0; c < 2; ++c)
      bfr[n][c] = *(const bf16x8*)&tsh[n * (HH * HH) + (c * 16 + lr) * 32 + lk * 8];

  const float* eb   = e + (size_t)b * (PP * NN * HH);
  float*       outb = out + (size_t)(b * PP + p1) * (PP * NN * HH);
  const f32x4  z    = {0.f, 0.f, 0.f, 0.f};
  for (int i = 0; i < 8; ++i) {
    const int m0 = (wv * 8 + i) * 16;
    #pragma unroll
    for (int n = 0; n < 8; ++n) {
      const float* ep = eb + (size_t)(((m0 + lr) * NN + n) * HH + lk * 8);
      const f4 e0 = *(const f4*)ep;
      const f4 e1 = *(const f4*)(ep + 4);
      bf16x8 a;
      a[0] = f2bf(e0[0]); a[1] = f2bf(e0[1]); a[2] = f2bf(e0[2]); a[3] = f2bf(e0[3]);
      a[4] = f2bf(e1[0]); a[5] = f2bf(e1[1]); a[6] = f2bf(e1[2]); a[7] = f2bf(e1[3]);
      const f32x4 c0 = __builtin_amdgcn_mfma_f32_16x16x32_bf16(bfr[n][0], a, z, 0, 0, 0);
      const f32x4 c1 = __builtin_amdgcn_mfma_f32_16x16x32_bf16(bfr[n][1], a, z, 0, 0, 0);
      float* op = outb + (size_t)(m0 + lr) * (NN * HH) + n * HH + lk * 4;
      *(f32x4*)op        = c0;
      *(f32x4*)(op + 16) = c1;
    }
  }
}

extern "C" void kernel_launch(void* const* d_in, const int* in_sizes, int n_in,
                              void* d_out, int out_size, void* d_ws, size_t ws_size,
                              hipStream_t stream) {
  const float* d = (const float*)d_in[0];
  const float* e = (const float*)d_in[1];
  const float* W = (const float*)d_in[2];
  float* out = (float*)d_out;

  const size_t tmp_bytes = (size_t)BB * PP * NN * HH * HH * sizeof(short); // 16.78 MB
  const size_t eb_bytes  = (size_t)BB * PP * NN * HH * sizeof(short);      // 512 KB
  const size_t wt_bytes  = (size_t)NN * HH * HH * HH * sizeof(float);      // 1 MB
  if (ws_size >= tmp_bytes + eb_bytes + wt_bytes) {
    short* tmpT = (short*)d_ws;
    short* eBf  = (short*)((char*)d_ws + tmp_bytes);
    float* WT   = (float*)((char*)d_ws + tmp_bytes + eb_bytes);
    aux_kernel<<<dim3(256 + 128), dim3(256), 0, stream>>>(W, e, WT, eBf);
    prep2_kernel<<<dim3(512), dim3(256), 0, stream>>>(d, WT, tmpT);
    vmain_kernel<<<dim3(BB * PP), dim3(256), 0, stream>>>(eBf, tmpT, out);
  } else {
    fused_kernel<<<dim3(BB * PP), dim3(256), 0, stream>>>(d, e, W, out);
  }
}

// Round 8
// 132.323 us; speedup vs baseline: 1.2514x; 1.2514x over previous
//
#include <hip/hip_runtime.h>

// dims from the reference
#define BB 2
#define PP 512
#define NN 8
#define HH 32

typedef float f4     __attribute__((ext_vector_type(4)));
typedef float f32x4  __attribute__((ext_vector_type(4)));
typedef short bf16x8 __attribute__((ext_vector_type(8)));

// float -> bf16 bits, round-nearest-even
__device__ __forceinline__ short f2bf(float f) {
  union { float f; unsigned u; } v; v.f = f;
  unsigned r = v.u + 0x7FFFu + ((v.u >> 16) & 1u);
  return (short)(r >> 16);
}

// ---------------------------------------------------------------------------
// Kernel 1: prep_all
//  blocks 0..511  : tmpT[b,p1,n,h3,h2] = bf16( sum_h1 d * W ) — W read
//                   DIRECTLY (no WT): lanes span h3 (contiguous in W),
//                   8 scalar loads per h1 at 128B immediate offsets.
//  blocks 512..639: eBf tiled bf16 layout:
//   eBf[((b*32+pt)*8+n)*512 + l*8 + j] = bf16(e[b, pt*16+(l&15), n, (l>>4)*8+j])
//   -> vmain's B-fragment is ONE dense 1KB wave load.
// ---------------------------------------------------------------------------
__global__ __launch_bounds__(256) void prep_all_kernel(
    const float* __restrict__ d, const float* __restrict__ W,
    const float* __restrict__ e, short* __restrict__ tmpT,
    short* __restrict__ eBf) {
  const int bid = blockIdx.x;
  const int t   = threadIdx.x;

  if (bid >= 512) {                    // ---- eBf tiled conversion ----
    const int ft = (bid - 512) * 256 + t;      // 0..32767
    const int l  = ft & 63;
    const int n  = (ft >> 6) & 7;
    const int pt = (ft >> 9) & 31;
    const int b  = ft >> 14;
    const float* src =
        e + (((size_t)(b * PP + pt * 16 + (l & 15)) * NN + n) * HH + (l >> 4) * 8);
    const f4 e0 = *(const f4*)src;
    const f4 e1 = *(const f4*)(src + 4);
    bf16x8 v;
    v[0] = f2bf(e0[0]); v[1] = f2bf(e0[1]); v[2] = f2bf(e0[2]); v[3] = f2bf(e0[3]);
    v[4] = f2bf(e1[0]); v[5] = f2bf(e1[1]); v[6] = f2bf(e1[2]); v[7] = f2bf(e1[3]);
    *(bf16x8*)(eBf + (size_t)ft * 8) = v;
    return;
  }

  // ---- prep part: block = (b, n-pair, 8 p1) ----
  const int b      = bid >> 8;
  const int rem    = bid & 255;
  const int npair  = rem >> 6;         // 0..3
  const int p1base = (rem & 63) * 8;

  __shared__ float dsh[2][32][8];      // [n'][h1][p1l]
  {
    const int h1 = t & 31, p1l = (t >> 5) & 7;
    #pragma unroll
    for (int r = 0; r < 2; ++r)
      dsh[r][h1][p1l] =
          d[(size_t)((b * PP + p1base + p1l) * NN + npair * 2 + r) * HH + h1];
  }
  __syncthreads();

  const int np  = t >> 7;              // 0/1
  const int h3  = (t >> 2) & 31;
  const int h2g = t & 3;               // h2 base = h2g*8
  const int n   = npair * 2 + np;

  float acc[8][8];                     // [p1l][h2loc]
  #pragma unroll
  for (int p = 0; p < 8; ++p)
    #pragma unroll
    for (int q = 0; q < 8; ++q) acc[p][q] = 0.f;

  // W[n][h1][h2][h3]: fixed h3, h2 = h2g*8 + q -> 8 scalar loads/h1 at
  // immediate offsets q*128B; lanes contiguous over h3 (coalesced).
  const float* wb = W + (size_t)n * 32768 + h2g * 8 * 32 + h3;
  for (int h1 = 0; h1 < 32; ++h1) {
    const float* wr = wb + (size_t)h1 * 1024;
    float wq[8];
    #pragma unroll
    for (int q = 0; q < 8; ++q) wq[q] = wr[q * 32];
    const f4 d0 = *(const f4*)&dsh[np][h1][0];
    const f4 d1 = *(const f4*)&dsh[np][h1][4];
    #pragma unroll
    for (int p = 0; p < 4; ++p) {
      #pragma unroll
      for (int q = 0; q < 4; ++q) {
        acc[p][q]         = fmaf(d0[p], wq[q],     acc[p][q]);
        acc[p][q + 4]     = fmaf(d0[p], wq[q + 4], acc[p][q + 4]);
        acc[p + 4][q]     = fmaf(d1[p], wq[q],     acc[p + 4][q]);
        acc[p + 4][q + 4] = fmaf(d1[p], wq[q + 4], acc[p + 4][q + 4]);
      }
    }
  }

  const size_t obase =
      ((size_t)(b * PP + p1base) * NN + n) * (HH * HH) + h3 * 32 + h2g * 8;
  #pragma unroll
  for (int p = 0; p < 8; ++p) {
    bf16x8 v;
    #pragma unroll
    for (int q = 0; q < 8; ++q) v[q] = f2bf(acc[p][q]);
    *(bf16x8*)(tmpT + obase + (size_t)p * (NN * HH * HH)) = v;
  }
}

// ---------------------------------------------------------------------------
// Kernel 2: vmain v8 — R3 structure (best verified) + dense eBf B-loads.
//   A-frags pinned in VGPRs (bfr[8][2], loaded once from tmpT).
//   B-frags: single dense 1KB wave load from tiled eBf (was 16x64B scatter).
//   Epilogue: XOR-swizzled per-wave LDS transpose (32KB lbuf), 2x512B-dense
//   dwordx4 stores. 4 blocks/CU. Plain cached stores (NT hurt, R4).
// ---------------------------------------------------------------------------
__global__ __launch_bounds__(256, 4) void vmain_kernel(
    const short* __restrict__ eBf, const short* __restrict__ tmpT,
    float* __restrict__ out) {
  const int bid = blockIdx.x;
  const int b   = bid >> 9;
  const int p1  = bid & 511;
  const int t   = threadIdx.x;
  const int wv  = t >> 6;
  const int l   = t & 63;
  const int lr  = l & 15;
  const int lk  = l >> 4;

  __shared__ float lbuf[4][16][128];   // 32 KB: per-wave transpose buffers
  float* wl = &lbuf[wv][0][0];

  // A-fragments: T^T rows h3 = c*16 + lr, k = h2 = 8*lk + j (contiguous 16B)
  bf16x8 bfr[8][2];
  const short* tb = tmpT + (size_t)(b * PP + p1) * (NN * HH * HH);
  #pragma unroll
  for (int n = 0; n < 8; ++n)
    #pragma unroll
    for (int c = 0; c < 2; ++c)
      bfr[n][c] = *(const bf16x8*)(tb + n * (HH * HH) + (c * 16 + lr) * 32 + lk * 8);

  const short* eb   = eBf + (size_t)b * (32 * NN * 512);
  float*       outb = out + (size_t)(b * PP + p1) * (PP * NN * HH);
  const f32x4  z    = {0.f, 0.f, 0.f, 0.f};

  for (int i = 0; i < 8; ++i) {
    const int pt = wv * 8 + i;         // p2 tile index
    const int m0 = pt * 16;
    #pragma unroll
    for (int half = 0; half < 2; ++half) {
      const int n0 = half * 4;
      #pragma unroll
      for (int nn = 0; nn < 4; ++nn) {
        const int n = n0 + nn;
        // dense 1KB wave load: lane l -> e[b, m0+(l&15), n, (l>>4)*8+j]
        const bf16x8 a =
            *(const bf16x8*)(eb + (((size_t)(pt * NN + n)) << 9) + l * 8);
        const f32x4 c0 = __builtin_amdgcn_mfma_f32_16x16x32_bf16(bfr[n][0], a, z, 0, 0, 0);
        const f32x4 c1 = __builtin_amdgcn_mfma_f32_16x16x32_bf16(bfr[n][1], a, z, 0, 0, 0);
        const int s0 = (nn * 8 + lk)     ^ (lr & 7);
        const int s1 = (nn * 8 + 4 + lk) ^ (lr & 7);
        *(f32x4*)(wl + lr * 128 + s0 * 4) = c0;
        *(f32x4*)(wl + lr * 128 + s1 * 4) = c1;
      }
      #pragma unroll
      for (int j = 0; j < 8; ++j) {
        const int row  = 2 * j + (l >> 5);
        const int slot = l & 31;
        const f32x4 v = *(const f32x4*)(wl + row * 128 + ((slot ^ (row & 7)) * 4));
        *(f32x4*)(outb + (size_t)(m0 + row) * (NN * HH) + n0 * HH + slot * 4) = v;
      }
    }
  }
}

// ---------------------------------------------------------------------------
// Fallback (no/small ws): self-contained fused kernel (correct, slower).
// ---------------------------------------------------------------------------
__global__ __launch_bounds__(256, 4) void fused_kernel(
    const float* __restrict__ d, const float* __restrict__ e,
    const float* __restrict__ W, float* __restrict__ out) {
  const int bid = blockIdx.x;
  const int b   = bid >> 9;
  const int p1  = bid & 511;
  const int t   = threadIdx.x;

  __shared__ float dsh[NN * HH];
  __shared__ short tsh[NN * HH * HH];
  dsh[t] = d[(size_t)(b * PP + p1) * (NN * HH) + t];
  __syncthreads();

  const int h3  = t & 31;
  const int h2b = t >> 5;
  for (int n = 0; n < 8; ++n) {
    f4 dv[8];
    #pragma unroll
    for (int j = 0; j < 8; ++j) dv[j] = *(const f4*)&dsh[n * 32 + j * 4];
    const float* Wn = W + (size_t)n * (HH * HH * HH);
    #pragma unroll
    for (int h2s = 0; h2s < 4; ++h2s) {
      const int h2 = h2s * 8 + h2b;
      float acc = 0.f;
      #pragma unroll
      for (int j = 0; j < 8; ++j)
        #pragma unroll
        for (int k = 0; k < 4; ++k)
          acc = fmaf(dv[j][k], Wn[(j * 4 + k) * 1024 + h2 * 32 + h3], acc);
      tsh[n * 1024 + h3 * 32 + h2] = f2bf(acc);
    }
  }
  __syncthreads();

  const int wv = t >> 6;
  const int l  = t & 63;
  const int lr = l & 15;
  const int lk = l >> 4;
  bf16x8 bfr[8][2];
  #pragma unroll
  for (int n = 0; n < 8; ++n)
    #pragma unroll
    for (int c = 0; c < 2; ++c)
      bfr[n][c] = *(const bf16x8*)&tsh[n * (HH * HH) + (c * 16 + lr) * 32 + lk * 8];

  const float* eb   = e + (size_t)b * (PP * NN * HH);
  float*       outb = out + (size_t)(b * PP + p1) * (PP * NN * HH);
  const f32x4  z    = {0.f, 0.f, 0.f, 0.f};
  for (int i = 0; i < 8; ++i) {
    const int m0 = (wv * 8 + i) * 16;
    #pragma unroll
    for (int n = 0; n < 8; ++n) {
      const float* ep = eb + (size_t)(((m0 + lr) * NN + n) * HH + lk * 8);
      const f4 e0 = *(const f4*)ep;
      const f4 e1 = *(const f4*)(ep + 4);
      bf16x8 a;
      a[0] = f2bf(e0[0]); a[1] = f2bf(e0[1]); a[2] = f2bf(e0[2]); a[3] = f2bf(e0[3]);
      a[4] = f2bf(e1[0]); a[5] = f2bf(e1[1]); a[6] = f2bf(e1[2]); a[7] = f2bf(e1[3]);
      const f32x4 c0 = __builtin_amdgcn_mfma_f32_16x16x32_bf16(bfr[n][0], a, z, 0, 0, 0);
      const f32x4 c1 = __builtin_amdgcn_mfma_f32_16x16x32_bf16(bfr[n][1], a, z, 0, 0, 0);
      float* op = outb + (size_t)(m0 + lr) * (NN * HH) + n * HH + lk * 4;
      *(f32x4*)op        = c0;
      *(f32x4*)(op + 16) = c1;
    }
  }
}

extern "C" void kernel_launch(void* const* d_in, const int* in_sizes, int n_in,
                              void* d_out, int out_size, void* d_ws, size_t ws_size,
                              hipStream_t stream) {
  const float* d = (const float*)d_in[0];
  const float* e = (const float*)d_in[1];
  const float* W = (const float*)d_in[2];
  float* out = (float*)d_out;

  const size_t tmp_bytes = (size_t)BB * PP * NN * HH * HH * sizeof(short); // 16.78 MB
  const size_t eb_bytes  = (size_t)BB * PP * NN * HH * sizeof(short);      // 512 KB
  if (ws_size >= tmp_bytes + eb_bytes) {
    short* tmpT = (short*)d_ws;
    short* eBf  = (short*)((char*)d_ws + tmp_bytes);
    prep_all_kernel<<<dim3(512 + 128), dim3(256), 0, stream>>>(d, W, e, tmpT, eBf);
    vmain_kernel<<<dim3(BB * PP), dim3(256), 0, stream>>>(eBf, tmpT, out);
  } else {
    fused_kernel<<<dim3(BB * PP), dim3(256), 0, stream>>>(d, e, W, out);
  }
}